// Round 18
// baseline (233.324 us; speedup 1.0000x reference)
//
#include <hip/hip_runtime.h>

#define K_DIM 512
#define S_DIM 64
#define T_LEN 64
#define BW    16      // sequences per workgroup
#define NWG   32      // 32 workgroups x 16 seqs = 512

typedef float f32x4 __attribute__((ext_vector_type(4)));
typedef float f32x2 __attribute__((ext_vector_type(2)));
typedef short bf16x8 __attribute__((ext_vector_type(8)));
typedef long  i64x2 __attribute__((ext_vector_type(2)));

__device__ __forceinline__ short f2bf(float f) {
    unsigned u = __builtin_bit_cast(unsigned, f);
    u += 0x7fffu + ((u >> 16) & 1u);   // round-to-nearest-even
    return (short)(u >> 16);
}
__device__ __forceinline__ char f2fp8(float f) {   // OCP e4m3 on gfx950
    return (char)__builtin_amdgcn_cvt_pk_fp8_f32(f, f, 0, false);
}

// ---------------- pre-pass: fp8 A + bf16 Ceff + packed {pi, pi*Bt} ----------------
__global__ void ssm_prep(const float* __restrict__ A, const float* __restrict__ B,
                         const float* __restrict__ C, const float* __restrict__ Pp,
                         char* __restrict__ A8, short* __restrict__ Ceff16,
                         f32x2* __restrict__ PPB) {
    int i = blockIdx.x * blockDim.x + threadIdx.x;
    int stride = gridDim.x * blockDim.x;
    for (int idx = i; idx < K_DIM * K_DIM; idx += stride)
        A8[idx] = f2fp8(A[idx]);
    for (int idx = i; idx < S_DIM * K_DIM; idx += stride) {
        int s = idx >> 9;               // K_DIM == 512
        int k = idx & (K_DIM - 1);
        float p = 1.0f / (1.0f + expf(-Pp[idx]));
        Ceff16[idx] = f2bf(C[idx] * p);
        PPB[idx] = (f32x2){p, p * B[k * S_DIM + s]};   // {pi, pi*Bt[tok][k]}
    }
}

#define MFMA_(xa, fb, acc) acc = __builtin_amdgcn_mfma_f32_16x16x32_bf16(xa, fb, acc, 0, 0, 0)
#define MFMA8(xj, aj, acc) acc = __builtin_amdgcn_mfma_f32_16x16x32_fp8_fp8(xj, aj, acc, 0, 0, 0)

// stream macro-slice m (K=64 chunk): 4 nt-rows x dwordx4 (16 fp8 = 2 k-slices)
#define LOADM(m) \
    i64x2 ga_##m = *(const i64x2*)(a8P0 + (m) * 64); \
    i64x2 gb_##m = *(const i64x2*)(a8P1 + (m) * 64); \
    i64x2 gc_##m = *(const i64x2*)(a8P2 + (m) * 64); \
    i64x2 gd_##m = *(const i64x2*)(a8P3 + (m) * 64);

// consume macro m: 1 LDS x-read (16B = both k-slices), 8 fp8 MFMAs
#define COMPM(m) { \
    i64x2 xv = *(const i64x2*)&Xb8[lr][(m) * 64 + 16 * lg]; \
    MFMA8(xv[0], ga_##m[0], acc0); MFMA8(xv[1], ga_##m[1], acc0); \
    MFMA8(xv[0], gb_##m[0], acc1); MFMA8(xv[1], gb_##m[1], acc1); \
    MFMA8(xv[0], gc_##m[0], acc2); MFMA8(xv[1], gc_##m[1], acc2); \
    MFMA8(xv[0], gd_##m[0], acc3); MFMA8(xv[1], gd_##m[1], acc3); }

// consume LDS-resident macro m (5..7): lane l's 16B at Aq8[w][m-5][nt][l]
#define COMPML(m) { \
    i64x2 xv = *(const i64x2*)&Xb8[lr][(m) * 64 + 16 * lg]; \
    i64x2 f0 = *(const i64x2*)&Aq8[w][(m) - 5][0][l][0]; \
    i64x2 f1 = *(const i64x2*)&Aq8[w][(m) - 5][1][l][0]; \
    i64x2 f2 = *(const i64x2*)&Aq8[w][(m) - 5][2][l][0]; \
    i64x2 f3 = *(const i64x2*)&Aq8[w][(m) - 5][3][l][0]; \
    MFMA8(xv[0], f0[0], acc0); MFMA8(xv[1], f0[1], acc0); \
    MFMA8(xv[0], f1[0], acc1); MFMA8(xv[1], f1[1], acc1); \
    MFMA8(xv[0], f2[0], acc2); MFMA8(xv[1], f2[1], acc2); \
    MFMA8(xv[0], f3[0], acc3); MFMA8(xv[1], f3[1], acc3); }

// raw barrier: drain LDS ops only; wave-private vmem loads ride across
#define LBAR asm volatile("s_waitcnt lgkmcnt(0)\ns_barrier" ::: "memory")

// ---------------- main: 32 WGs x 512 threads (8 waves), 16 seqs/WG, 64 steps ----------------
// R17 + 3 scheduling fixes: (1) ppv gathers at step start (covered by P1+P2;
// fits now because fp8 halved in-flight regs), (2) softmax across all 8 waves
// (2 seqs/wave, 32 lanes/seq), (3) P1 dual accumulator chains.
__global__ __launch_bounds__(512) __attribute__((amdgpu_waves_per_eu(2, 2)))
void ssm_main(
    const char*  __restrict__ A8,      // [K][K] fp8 e4m3 row-major
    const short* __restrict__ Ceff16,  // [S][K] bf16
    const f32x2* __restrict__ PPB,     // [S][K] {pi, pi*Bt}
    const float* __restrict__ init,    // [K]
    const int*   __restrict__ tokens,  // [BSZ][T]
    float*       __restrict__ out)     // [BSZ]
{
    __shared__ char  Aq8[8][3][4][64][16];  // 96 KB: A cols 320..512 fp8, fragment order
    __shared__ short Xb[BW][520];           // 16.6 KB bf16 state (logits path)
    __shared__ char  Xb8[BW][528];          //  8.4 KB fp8 state (update path)
    __shared__ float Lg[2][BW][68];         //  8.7 KB logits partials (2 K-halves)
    __shared__ int   tokS[BW][T_LEN];       //  4.1 KB   (total ~134 KB -> 1 WG/CU)

    const int tid = threadIdx.x;
    const int w  = tid >> 6;     // wave 0..7, owns k-range [w*64, w*64+64)
    const int l  = tid & 63;
    const int lg = l >> 4;
    const int lr = l & 15;
    const int b0 = blockIdx.x * BW;

    for (int idx = tid; idx < BW * T_LEN; idx += 512) {
        int r = idx >> 6, t = idx & 63;
        tokS[r][t] = tokens[(b0 + r) * T_LEN + t];
    }
    for (int idx = tid; idx < BW * K_DIM; idx += 512) {
        int r = idx >> 9, k = idx & (K_DIM - 1);
        float iv = init[k];
        Xb[r][k]  = f2bf(iv);
        Xb8[r][k] = f2fp8(iv);
    }
    // stage A fp8 macros 5..7 into LDS in fragment order (once; reused 64 steps)
    for (int idx = tid; idx < 6144; idx += 512) {
        int w2 = idx / 768, rem = idx % 768;
        int m2 = rem >> 8, rem2 = rem & 255;
        int q2 = rem2 >> 6, l2 = rem2 & 63;
        *(i64x2*)&Aq8[w2][m2][q2][l2][0] =
            *(const i64x2*)(A8 + (w2 * 64 + q2 * 16 + (l2 & 15)) * K_DIM
                            + (5 + m2) * 64 + (l2 >> 4) * 16);
    }
    // fp32 master state: xm[nt][e] = x[seq=4*lg+e][k = w*64 + nt*16 + lr]
    float xm[4][4];
    #pragma unroll
    for (int nt = 0; nt < 4; ++nt) {
        float iv = init[w * 64 + nt * 16 + lr];
        #pragma unroll
        for (int e = 0; e < 4; ++e) xm[nt][e] = iv;
    }

    const int sq = w & 3;    // logits s-tile
    const int kh = w >> 2;   // logits K-half

    // per-lane fp8 A bases (one per nt-quarter of the wave's 64 rows)
    const char* a8P0 = A8 + (w * 64 +      lr) * K_DIM + 16 * lg;
    const char* a8P1 = A8 + (w * 64 + 16 + lr) * K_DIM + 16 * lg;
    const char* a8P2 = A8 + (w * 64 + 32 + lr) * K_DIM + 16 * lg;
    const char* a8P3 = A8 + (w * 64 + 48 + lr) * K_DIM + 16 * lg;
    const short* cP  = Ceff16 + (sq * 16 + lr) * K_DIM + kh * 256 + 8 * lg;

    float llacc = 0.0f;
    __syncthreads();

    for (int t = 0; t < T_LEN; ++t) {
        // ---- gating gathers issued FIRST: P1+P2 (~>1000 cy) cover their latency
        int mytok[4];
        #pragma unroll
        for (int e = 0; e < 4; ++e) mytok[e] = tokS[4 * lg + e][t];
        f32x2 ppv[4][4];
        #pragma unroll
        for (int nt = 0; nt < 4; ++nt) {
            int k = w * 64 + nt * 16 + lr;
            #pragma unroll
            for (int e = 0; e < 4; ++e)
                ppv[nt][e] = PPB[mytok[e] * K_DIM + k];
        }

        // ---- prime 2 macro-slices; latency hides under P1
        LOADM(0) LOADM(1)

        // ---- P1: logits partial GEMM (K-half kh), bf16, dual accumulator chains
        f32x4 lga0 = {0.f, 0.f, 0.f, 0.f};
        f32x4 lga1 = {0.f, 0.f, 0.f, 0.f};
        #pragma unroll
        for (int i = 0; i < 4; ++i) {
            bf16x8 cbA = *(const bf16x8*)(cP + (2 * i) * 32);
            bf16x8 xaA = *(const bf16x8*)&Xb[lr][kh * 256 + (2 * i) * 32 + 8 * lg];
            MFMA_(xaA, cbA, lga0);
            bf16x8 cbB = *(const bf16x8*)(cP + (2 * i + 1) * 32);
            bf16x8 xaB = *(const bf16x8*)&Xb[lr][kh * 256 + (2 * i + 1) * 32 + 8 * lg];
            MFMA_(xaB, cbB, lga1);
        }
        #pragma unroll
        for (int e = 0; e < 4; ++e)
            Lg[kh][4 * lg + e][sq * 16 + lr] = lga0[e] + lga1[e];

        // ---- P2: update GEMM fp8, macros 0..4 streamed depth-2
        f32x4 acc0 = {0.f, 0.f, 0.f, 0.f};
        f32x4 acc1 = {0.f, 0.f, 0.f, 0.f};
        f32x4 acc2 = {0.f, 0.f, 0.f, 0.f};
        f32x4 acc3 = {0.f, 0.f, 0.f, 0.f};
        COMPM(0)  LOADM(2)
        COMPM(1)  LOADM(3)
        COMPM(2)  LOADM(4)
        COMPM(3)
        COMPM(4)
        // ---- macros 5..7 from LDS (zero vmem)
        COMPML(5) COMPML(6) COMPML(7)
        LBAR;   // barrier1: Xb/Xb8 reads done, Lg visible

        // ---- P3: gating in fp32, rewrite Xb (bf16) + Xb8 (fp8)
        #pragma unroll
        for (int nt = 0; nt < 4; ++nt) {
            int k = w * 64 + nt * 16 + lr;
            #pragma unroll
            for (int e = 0; e < 4; ++e) {
                float a  = (nt == 0) ? acc0[e] : (nt == 1) ? acc1[e]
                         : (nt == 2) ? acc2[e] : acc3[e];
                float nx = xm[nt][e] + ppv[nt][e][0] * (a - xm[nt][e]) + ppv[nt][e][1];
                xm[nt][e] = nx;
                Xb[4 * lg + e][k]  = f2bf(nx);
                Xb8[4 * lg + e][k] = f2fp8(nx);
            }
        }
        // ---- softmax across ALL 8 waves: 2 seqs/wave, 32 lanes/seq, 2 logits/lane
        {
            int b = w * 2 + (l >> 5);
            int i = l & 31;
            float v0 = Lg[0][b][i * 2]     + Lg[1][b][i * 2];
            float v1 = Lg[0][b][i * 2 + 1] + Lg[1][b][i * 2 + 1];
            float m = fmaxf(v0, v1);
            m = fmaxf(m, __shfl_xor(m, 1));
            m = fmaxf(m, __shfl_xor(m, 2));
            m = fmaxf(m, __shfl_xor(m, 4));
            m = fmaxf(m, __shfl_xor(m, 8));
            m = fmaxf(m, __shfl_xor(m, 16));
            float sum = expf(v0 - m) + expf(v1 - m);
            sum += __shfl_xor(sum, 1);
            sum += __shfl_xor(sum, 2);
            sum += __shfl_xor(sum, 4);
            sum += __shfl_xor(sum, 8);
            sum += __shfl_xor(sum, 16);
            int tok = tokS[b][t];
            float sel = (i == (tok >> 1)) ? ((tok & 1) ? v1 : v0) : 0.0f;
            sel += __shfl_xor(sel, 1);
            sel += __shfl_xor(sel, 2);
            sel += __shfl_xor(sel, 4);
            sel += __shfl_xor(sel, 8);
            sel += __shfl_xor(sel, 16);
            llacc += sel - m - logf(sum);
        }
        LBAR;   // barrier2: new Xb/Xb8 visible, Lg consumed
    }

    if ((l & 31) == 0)
        out[b0 + w * 2 + (l >> 5)] = llacc;
}

extern "C" void kernel_launch(void* const* d_in, const int* in_sizes, int n_in,
                              void* d_out, int out_size, void* d_ws, size_t ws_size,
                              hipStream_t stream) {
    const float* A  = (const float*)d_in[0];   // (512,512)
    const float* B  = (const float*)d_in[1];   // (512,64)
    const float* C  = (const float*)d_in[2];   // (64,512)
    const float* Pp = (const float*)d_in[3];   // (64,512)
    const float* init = (const float*)d_in[4]; // (512,)
    const int* tokens = (const int*)d_in[5];   // (512,64)
    float* out = (float*)d_out;

    // workspace layout (needs 589,824 bytes)
    char*  A8     = (char*)d_ws;                               // 512*512*1 = 262144
    short* Ceff16 = (short*)((char*)d_ws + 262144);            // 64*512*2  =  65536
    f32x2* PPB    = (f32x2*)((char*)d_ws + 327680);            // 64*512*8  = 262144

    ssm_prep<<<256, 256, 0, stream>>>(A, B, C, Pp, A8, Ceff16, PPB);
    ssm_main<<<NWG, 512, 0, stream>>>(A8, Ceff16, PPB, init, tokens, out);
}

// Round 19
// 214.537 us; speedup vs baseline: 1.0876x; 1.0876x over previous
//
#include <hip/hip_runtime.h>

#define K_DIM 512
#define S_DIM 64
#define T_LEN 64
#define BW    16      // sequences per workgroup
#define NWG   32      // 32 workgroups x 16 seqs = 512

typedef float f32x4 __attribute__((ext_vector_type(4)));
typedef float f32x2 __attribute__((ext_vector_type(2)));
typedef short bf16x8 __attribute__((ext_vector_type(8)));
typedef long  i64x2 __attribute__((ext_vector_type(2)));

__device__ __forceinline__ short f2bf(float f) {
    unsigned u = __builtin_bit_cast(unsigned, f);
    u += 0x7fffu + ((u >> 16) & 1u);   // round-to-nearest-even
    return (short)(u >> 16);
}
__device__ __forceinline__ char f2fp8(float f) {   // OCP e4m3 on gfx950
    return (char)__builtin_amdgcn_cvt_pk_fp8_f32(f, f, 0, false);
}

// ---------------- pre-pass: fp8 A + bf16 Ceff + packed {pi, pi*Bt} ----------------
__global__ void ssm_prep(const float* __restrict__ A, const float* __restrict__ B,
                         const float* __restrict__ C, const float* __restrict__ Pp,
                         char* __restrict__ A8, short* __restrict__ Ceff16,
                         f32x2* __restrict__ PPB) {
    int i = blockIdx.x * blockDim.x + threadIdx.x;
    int stride = gridDim.x * blockDim.x;
    for (int idx = i; idx < K_DIM * K_DIM; idx += stride)
        A8[idx] = f2fp8(A[idx]);
    for (int idx = i; idx < S_DIM * K_DIM; idx += stride) {
        int s = idx >> 9;               // K_DIM == 512
        int k = idx & (K_DIM - 1);
        float p = 1.0f / (1.0f + expf(-Pp[idx]));
        Ceff16[idx] = f2bf(C[idx] * p);
        PPB[idx] = (f32x2){p, p * B[k * S_DIM + s]};   // {pi, pi*Bt[tok][k]}
    }
}

#define MFMA_(xa, fb, acc) acc = __builtin_amdgcn_mfma_f32_16x16x32_bf16(xa, fb, acc, 0, 0, 0)
#define MFMA8(xj, aj, acc) acc = __builtin_amdgcn_mfma_f32_16x16x32_fp8_fp8(xj, aj, acc, 0, 0, 0)

// stream macro-slice m (K=64 chunk): 4 nt-rows x dwordx4 (16 fp8 = 2 k-slices)
#define LOADM(m) \
    i64x2 ga_##m = *(const i64x2*)(a8P0 + (m) * 64); \
    i64x2 gb_##m = *(const i64x2*)(a8P1 + (m) * 64); \
    i64x2 gc_##m = *(const i64x2*)(a8P2 + (m) * 64); \
    i64x2 gd_##m = *(const i64x2*)(a8P3 + (m) * 64);

// consume macro m: 1 LDS x-read (16B = both k-slices), 8 fp8 MFMAs
#define COMPM(m) { \
    i64x2 xv = *(const i64x2*)&Xb8[lr][(m) * 64 + 16 * lg]; \
    MFMA8(xv[0], ga_##m[0], acc0); MFMA8(xv[1], ga_##m[1], acc0); \
    MFMA8(xv[0], gb_##m[0], acc1); MFMA8(xv[1], gb_##m[1], acc1); \
    MFMA8(xv[0], gc_##m[0], acc2); MFMA8(xv[1], gc_##m[1], acc2); \
    MFMA8(xv[0], gd_##m[0], acc3); MFMA8(xv[1], gd_##m[1], acc3); }

// consume LDS-resident macro m (5..7): lane l's 16B at Aq8[w][m-5][nt][l]
#define COMPML(m) { \
    i64x2 xv = *(const i64x2*)&Xb8[lr][(m) * 64 + 16 * lg]; \
    i64x2 f0 = *(const i64x2*)&Aq8[w][(m) - 5][0][l][0]; \
    i64x2 f1 = *(const i64x2*)&Aq8[w][(m) - 5][1][l][0]; \
    i64x2 f2 = *(const i64x2*)&Aq8[w][(m) - 5][2][l][0]; \
    i64x2 f3 = *(const i64x2*)&Aq8[w][(m) - 5][3][l][0]; \
    MFMA8(xv[0], f0[0], acc0); MFMA8(xv[1], f0[1], acc0); \
    MFMA8(xv[0], f1[0], acc1); MFMA8(xv[1], f1[1], acc1); \
    MFMA8(xv[0], f2[0], acc2); MFMA8(xv[1], f2[1], acc2); \
    MFMA8(xv[0], f3[0], acc3); MFMA8(xv[1], f3[1], acc3); }

// raw barrier: drain LDS ops only; wave-private vmem loads ride across
#define LBAR asm volatile("s_waitcnt lgkmcnt(0)\ns_barrier" ::: "memory")

// ---------------- main: 32 WGs x 512 threads (8 waves), 16 seqs/WG, 64 steps ----------------
// R17 + (1) 4-macro prime before P1: stream latency and P1's cb latency drain
// TOGETHER under one entry stall (vmcnt is FIFO, m135 -- co-priming loads that
// are all needed soon merges their stalls; R18's ppv-first abused the same
// property in the wrong direction), (2) 8-wave softmax (no idle bubble).
__global__ __launch_bounds__(512) __attribute__((amdgpu_waves_per_eu(2, 2)))
void ssm_main(
    const char*  __restrict__ A8,      // [K][K] fp8 e4m3 row-major
    const short* __restrict__ Ceff16,  // [S][K] bf16
    const f32x2* __restrict__ PPB,     // [S][K] {pi, pi*Bt}
    const float* __restrict__ init,    // [K]
    const int*   __restrict__ tokens,  // [BSZ][T]
    float*       __restrict__ out)     // [BSZ]
{
    __shared__ char  Aq8[8][3][4][64][16];  // 96 KB: A cols 320..512 fp8, fragment order
    __shared__ short Xb[BW][520];           // 16.6 KB bf16 state (logits path)
    __shared__ char  Xb8[BW][528];          //  8.4 KB fp8 state (update path)
    __shared__ float Lg[2][BW][68];         //  8.7 KB logits partials (2 K-halves)
    __shared__ int   tokS[BW][T_LEN];       //  4.1 KB   (total ~134 KB -> 1 WG/CU)

    const int tid = threadIdx.x;
    const int w  = tid >> 6;     // wave 0..7, owns k-range [w*64, w*64+64)
    const int l  = tid & 63;
    const int lg = l >> 4;
    const int lr = l & 15;
    const int b0 = blockIdx.x * BW;

    for (int idx = tid; idx < BW * T_LEN; idx += 512) {
        int r = idx >> 6, t = idx & 63;
        tokS[r][t] = tokens[(b0 + r) * T_LEN + t];
    }
    for (int idx = tid; idx < BW * K_DIM; idx += 512) {
        int r = idx >> 9, k = idx & (K_DIM - 1);
        float iv = init[k];
        Xb[r][k]  = f2bf(iv);
        Xb8[r][k] = f2fp8(iv);
    }
    // stage A fp8 macros 5..7 into LDS in fragment order (once; reused 64 steps)
    for (int idx = tid; idx < 6144; idx += 512) {
        int w2 = idx / 768, rem = idx % 768;
        int m2 = rem >> 8, rem2 = rem & 255;
        int q2 = rem2 >> 6, l2 = rem2 & 63;
        *(i64x2*)&Aq8[w2][m2][q2][l2][0] =
            *(const i64x2*)(A8 + (w2 * 64 + q2 * 16 + (l2 & 15)) * K_DIM
                            + (5 + m2) * 64 + (l2 >> 4) * 16);
    }
    // fp32 master state: xm[nt][e] = x[seq=4*lg+e][k = w*64 + nt*16 + lr]
    float xm[4][4];
    #pragma unroll
    for (int nt = 0; nt < 4; ++nt) {
        float iv = init[w * 64 + nt * 16 + lr];
        #pragma unroll
        for (int e = 0; e < 4; ++e) xm[nt][e] = iv;
    }

    const int sq = w & 3;    // logits s-tile
    const int kh = w >> 2;   // logits K-half

    // per-lane fp8 A bases (one per nt-quarter of the wave's 64 rows)
    const char* a8P0 = A8 + (w * 64 +      lr) * K_DIM + 16 * lg;
    const char* a8P1 = A8 + (w * 64 + 16 + lr) * K_DIM + 16 * lg;
    const char* a8P2 = A8 + (w * 64 + 32 + lr) * K_DIM + 16 * lg;
    const char* a8P3 = A8 + (w * 64 + 48 + lr) * K_DIM + 16 * lg;
    const short* cP  = Ceff16 + (sq * 16 + lr) * K_DIM + kh * 256 + 8 * lg;

    float llacc = 0.0f;
    __syncthreads();

    for (int t = 0; t < T_LEN; ++t) {
        // ---- prime 4 macro-slices (64 regs in flight); they drain together
        //      with P1's cb loads under P1's single entry stall
        LOADM(0) LOADM(1) LOADM(2) LOADM(3)

        // ---- P1: logits partial GEMM (K-half kh), bf16; cb from L2 (hot)
        f32x4 lga = {0.f, 0.f, 0.f, 0.f};
        #pragma unroll
        for (int i = 0; i < 8; ++i) {
            bf16x8 cb = *(const bf16x8*)(cP + i * 32);
            bf16x8 xa = *(const bf16x8*)&Xb[lr][kh * 256 + i * 32 + 8 * lg];
            MFMA_(xa, cb, lga);
        }
        #pragma unroll
        for (int e = 0; e < 4; ++e)
            Lg[kh][4 * lg + e][sq * 16 + lr] = lga[e];

        // ---- P2: macros 0..3 landed (zero exposure); macro 4 issued here
        f32x4 acc0 = {0.f, 0.f, 0.f, 0.f};
        f32x4 acc1 = {0.f, 0.f, 0.f, 0.f};
        f32x4 acc2 = {0.f, 0.f, 0.f, 0.f};
        f32x4 acc3 = {0.f, 0.f, 0.f, 0.f};
        COMPM(0)  LOADM(4)
        COMPM(1)
        COMPM(2)
        COMPM(3)
        COMPM(4)
        // ---- gating gathers: zero A-loads in flight; latency hides under LDS tail
        int mytok[4];
        #pragma unroll
        for (int e = 0; e < 4; ++e) mytok[e] = tokS[4 * lg + e][t];
        f32x2 ppv[4][4];
        #pragma unroll
        for (int nt = 0; nt < 4; ++nt) {
            int k = w * 64 + nt * 16 + lr;
            #pragma unroll
            for (int e = 0; e < 4; ++e)
                ppv[nt][e] = PPB[mytok[e] * K_DIM + k];
        }
        // ---- macros 5..7 from LDS (zero vmem)
        COMPML(5) COMPML(6) COMPML(7)
        LBAR;   // barrier1: Xb/Xb8 reads done, Lg visible

        // ---- P3: gating in fp32, rewrite Xb (bf16) + Xb8 (fp8)
        #pragma unroll
        for (int nt = 0; nt < 4; ++nt) {
            int k = w * 64 + nt * 16 + lr;
            #pragma unroll
            for (int e = 0; e < 4; ++e) {
                float a  = (nt == 0) ? acc0[e] : (nt == 1) ? acc1[e]
                         : (nt == 2) ? acc2[e] : acc3[e];
                float nx = xm[nt][e] + ppv[nt][e][0] * (a - xm[nt][e]) + ppv[nt][e][1];
                xm[nt][e] = nx;
                Xb[4 * lg + e][k]  = f2bf(nx);
                Xb8[4 * lg + e][k] = f2fp8(nx);
            }
        }
        // ---- softmax across ALL 8 waves: 2 seqs/wave, 32 lanes/seq, 2 logits/lane
        {
            int b = w * 2 + (l >> 5);
            int i = l & 31;
            float v0 = Lg[0][b][i * 2]     + Lg[1][b][i * 2];
            float v1 = Lg[0][b][i * 2 + 1] + Lg[1][b][i * 2 + 1];
            float m = fmaxf(v0, v1);
            m = fmaxf(m, __shfl_xor(m, 1));
            m = fmaxf(m, __shfl_xor(m, 2));
            m = fmaxf(m, __shfl_xor(m, 4));
            m = fmaxf(m, __shfl_xor(m, 8));
            m = fmaxf(m, __shfl_xor(m, 16));
            float sum = expf(v0 - m) + expf(v1 - m);
            sum += __shfl_xor(sum, 1);
            sum += __shfl_xor(sum, 2);
            sum += __shfl_xor(sum, 4);
            sum += __shfl_xor(sum, 8);
            sum += __shfl_xor(sum, 16);
            int tok = tokS[b][t];
            float sel = (i == (tok >> 1)) ? ((tok & 1) ? v1 : v0) : 0.0f;
            sel += __shfl_xor(sel, 1);
            sel += __shfl_xor(sel, 2);
            sel += __shfl_xor(sel, 4);
            sel += __shfl_xor(sel, 8);
            sel += __shfl_xor(sel, 16);
            llacc += sel - m - logf(sum);
        }
        LBAR;   // barrier2: new Xb/Xb8 visible, Lg consumed
    }

    if ((l & 31) == 0)
        out[b0 + w * 2 + (l >> 5)] = llacc;
}

extern "C" void kernel_launch(void* const* d_in, const int* in_sizes, int n_in,
                              void* d_out, int out_size, void* d_ws, size_t ws_size,
                              hipStream_t stream) {
    const float* A  = (const float*)d_in[0];   // (512,512)
    const float* B  = (const float*)d_in[1];   // (512,64)
    const float* C  = (const float*)d_in[2];   // (64,512)
    const float* Pp = (const float*)d_in[3];   // (64,512)
    const float* init = (const float*)d_in[4]; // (512,)
    const int* tokens = (const int*)d_in[5];   // (512,64)
    float* out = (float*)d_out;

    // workspace layout (needs 589,824 bytes)
    char*  A8     = (char*)d_ws;                               // 512*512*1 = 262144
    short* Ceff16 = (short*)((char*)d_ws + 262144);            // 64*512*2  =  65536
    f32x2* PPB    = (f32x2*)((char*)d_ws + 327680);            // 64*512*8  = 262144

    ssm_prep<<<256, 256, 0, stream>>>(A, B, C, Pp, A8, Ceff16, PPB);
    ssm_main<<<NWG, 512, 0, stream>>>(A8, Ceff16, PPB, init, tokens, out);
}

// Round 20
// 177.666 us; speedup vs baseline: 1.3133x; 1.2075x over previous
//
#include <hip/hip_runtime.h>

#define K_DIM 512
#define S_DIM 64
#define T_LEN 64
#define BW    16      // sequences per workgroup
#define NWG   32      // 32 workgroups x 16 seqs = 512

typedef float f32x4 __attribute__((ext_vector_type(4)));
typedef float f32x2 __attribute__((ext_vector_type(2)));
typedef long  i64x2 __attribute__((ext_vector_type(2)));

__device__ __forceinline__ char f2fp8(float f) {   // OCP e4m3 on gfx950
    return (char)__builtin_amdgcn_cvt_pk_fp8_f32(f, f, 0, false);
}

// ---------------- pre-pass: fp8 A + fp8 Ceff + packed {pi, pi*Bt} ----------------
__global__ void ssm_prep(const float* __restrict__ A, const float* __restrict__ B,
                         const float* __restrict__ C, const float* __restrict__ Pp,
                         char* __restrict__ A8, char* __restrict__ C8,
                         f32x2* __restrict__ PPB) {
    int i = blockIdx.x * blockDim.x + threadIdx.x;
    int stride = gridDim.x * blockDim.x;
    for (int idx = i; idx < K_DIM * K_DIM; idx += stride)
        A8[idx] = f2fp8(A[idx]);
    for (int idx = i; idx < S_DIM * K_DIM; idx += stride) {
        int s = idx >> 9;               // K_DIM == 512
        int k = idx & (K_DIM - 1);
        float p = 1.0f / (1.0f + expf(-Pp[idx]));
        C8[idx] = f2fp8(C[idx] * p);
        PPB[idx] = (f32x2){p, p * B[k * S_DIM + s]};   // {pi, pi*Bt[tok][k]}
    }
}

#define MFMA8(xj, aj, acc) acc = __builtin_amdgcn_mfma_f32_16x16x32_fp8_fp8(xj, aj, acc, 0, 0, 0)

// stream macro-slice m (K=64 chunk): 4 nt-rows x dwordx4 (16 fp8 = 2 k-slices)
#define LOADM(m) \
    i64x2 ga_##m = *(const i64x2*)(a8P0 + (m) * 64); \
    i64x2 gb_##m = *(const i64x2*)(a8P1 + (m) * 64); \
    i64x2 gc_##m = *(const i64x2*)(a8P2 + (m) * 64); \
    i64x2 gd_##m = *(const i64x2*)(a8P3 + (m) * 64);

// consume macro m: 1 LDS x-read (16B = both k-slices), 8 fp8 MFMAs
#define COMPM(m) { \
    i64x2 xv = *(const i64x2*)&Xb8[lr][(m) * 64 + 16 * lg]; \
    MFMA8(xv[0], ga_##m[0], acc0); MFMA8(xv[1], ga_##m[1], acc0); \
    MFMA8(xv[0], gb_##m[0], acc1); MFMA8(xv[1], gb_##m[1], acc1); \
    MFMA8(xv[0], gc_##m[0], acc2); MFMA8(xv[1], gc_##m[1], acc2); \
    MFMA8(xv[0], gd_##m[0], acc3); MFMA8(xv[1], gd_##m[1], acc3); }

// consume LDS-resident macro m (4..7): lane l's 16B at Aq8[w][m-4][nt][l]
#define COMPML(m) { \
    i64x2 xv = *(const i64x2*)&Xb8[lr][(m) * 64 + 16 * lg]; \
    i64x2 f0 = *(const i64x2*)&Aq8[w][(m) - 4][0][l][0]; \
    i64x2 f1 = *(const i64x2*)&Aq8[w][(m) - 4][1][l][0]; \
    i64x2 f2 = *(const i64x2*)&Aq8[w][(m) - 4][2][l][0]; \
    i64x2 f3 = *(const i64x2*)&Aq8[w][(m) - 4][3][l][0]; \
    MFMA8(xv[0], f0[0], acc0); MFMA8(xv[1], f0[1], acc0); \
    MFMA8(xv[0], f1[0], acc1); MFMA8(xv[1], f1[1], acc1); \
    MFMA8(xv[0], f2[0], acc2); MFMA8(xv[1], f2[1], acc2); \
    MFMA8(xv[0], f3[0], acc3); MFMA8(xv[1], f3[1], acc3); }

// raw barrier: drain LDS ops only; wave-private vmem loads ride across
#define LBAR asm volatile("s_waitcnt lgkmcnt(0)\ns_barrier" ::: "memory")

// ---------------- main: 32 WGs x 512 threads (8 waves), 16 seqs/WG, 64 steps ----------------
// R17 schedule shape, single change-set: the x-state is fp8-only (no bf16 copy).
// P1 logits GEMM runs fp8xfp8 (Ceff pre-converted). Saves per thread/step:
// 16 f2bf + 16 ds_write_b16 + 4 cb loads + 4 LDS x-reads. Freed LDS funds a
// 4th resident A-macro (stream 4, resident 4). Both fp8 operands everywhere
// use k = 64m + 16*lg + 8j + e -> layout-safe without knowing HW slot order.
__global__ __launch_bounds__(512) __attribute__((amdgpu_waves_per_eu(2, 2)))
void ssm_main(
    const char*  __restrict__ A8,      // [K][K] fp8 e4m3 row-major
    const char*  __restrict__ C8,      // [S][K] fp8 e4m3 (C * sigmoid(pi))
    const f32x2* __restrict__ PPB,     // [S][K] {pi, pi*Bt}
    const float* __restrict__ init,    // [K]
    const int*   __restrict__ tokens,  // [BSZ][T]
    float*       __restrict__ out)     // [BSZ]
{
    __shared__ char  Aq8[8][4][4][64][16];  // 128 KB: A cols 256..512 fp8, fragment order
    __shared__ char  Xb8[BW][528];          //  8.4 KB fp8 state (both GEMM paths)
    __shared__ float Lg[2][BW][68];         //  8.7 KB logits partials (2 K-halves)
    __shared__ int   tokS[BW][T_LEN];       //  4.1 KB   (total ~149 KB -> 1 WG/CU)

    const int tid = threadIdx.x;
    const int w  = tid >> 6;     // wave 0..7, owns k-range [w*64, w*64+64)
    const int l  = tid & 63;
    const int lg = l >> 4;
    const int lr = l & 15;
    const int b0 = blockIdx.x * BW;

    for (int idx = tid; idx < BW * T_LEN; idx += 512) {
        int r = idx >> 6, t = idx & 63;
        tokS[r][t] = tokens[(b0 + r) * T_LEN + t];
    }
    for (int idx = tid; idx < BW * K_DIM; idx += 512) {
        int r = idx >> 9, k = idx & (K_DIM - 1);
        Xb8[r][k] = f2fp8(init[k]);
    }
    // stage A fp8 macros 4..7 into LDS in fragment order (once; reused 64 steps)
    for (int idx = tid; idx < 8192; idx += 512) {
        int w2 = idx >> 10, rem = idx & 1023;
        int m2 = rem >> 8, rem2 = rem & 255;
        int q2 = rem2 >> 6, l2 = rem2 & 63;
        *(i64x2*)&Aq8[w2][m2][q2][l2][0] =
            *(const i64x2*)(A8 + (w2 * 64 + q2 * 16 + (l2 & 15)) * K_DIM
                            + (4 + m2) * 64 + (l2 >> 4) * 16);
    }
    // fp32 master state: xm[nt][e] = x[seq=4*lg+e][k = w*64 + nt*16 + lr]
    float xm[4][4];
    #pragma unroll
    for (int nt = 0; nt < 4; ++nt) {
        float iv = init[w * 64 + nt * 16 + lr];
        #pragma unroll
        for (int e = 0; e < 4; ++e) xm[nt][e] = iv;
    }

    const int sq = w & 3;    // logits s-tile
    const int kh = w >> 2;   // logits K-half

    // per-lane fp8 A bases (one per nt-quarter of the wave's 64 rows)
    const char* a8P0 = A8 + (w * 64 +      lr) * K_DIM + 16 * lg;
    const char* a8P1 = A8 + (w * 64 + 16 + lr) * K_DIM + 16 * lg;
    const char* a8P2 = A8 + (w * 64 + 32 + lr) * K_DIM + 16 * lg;
    const char* a8P3 = A8 + (w * 64 + 48 + lr) * K_DIM + 16 * lg;
    const char* c8P  = C8 + (sq * 16 + lr) * K_DIM + kh * 256 + 16 * lg;

    float llacc = 0.0f;
    __syncthreads();

    for (int t = 0; t < T_LEN; ++t) {
        // ---- prime 2 macro-slices; latency hides under P1
        LOADM(0) LOADM(1)

        // ---- P1: logits partial GEMM (K-half kh), fp8; cb from L2 (hot, 4 loads)
        f32x4 lga = {0.f, 0.f, 0.f, 0.f};
        #pragma unroll
        for (int j = 0; j < 4; ++j) {
            i64x2 cv = *(const i64x2*)(c8P + j * 64);
            i64x2 xv = *(const i64x2*)&Xb8[lr][kh * 256 + j * 64 + 16 * lg];
            MFMA8(xv[0], cv[0], lga);
            MFMA8(xv[1], cv[1], lga);
        }
        #pragma unroll
        for (int e = 0; e < 4; ++e)
            Lg[kh][4 * lg + e][sq * 16 + lr] = lga[e];

        // ---- P2: update GEMM fp8, macros 0..3 streamed depth-2
        f32x4 acc0 = {0.f, 0.f, 0.f, 0.f};
        f32x4 acc1 = {0.f, 0.f, 0.f, 0.f};
        f32x4 acc2 = {0.f, 0.f, 0.f, 0.f};
        f32x4 acc3 = {0.f, 0.f, 0.f, 0.f};
        COMPM(0)  LOADM(2)
        COMPM(1)  LOADM(3)
        COMPM(2)
        COMPM(3)
        // ---- gating gathers: zero A-loads in flight; latency hides under LDS tail
        int mytok[4];
        #pragma unroll
        for (int e = 0; e < 4; ++e) mytok[e] = tokS[4 * lg + e][t];
        f32x2 ppv[4][4];
        #pragma unroll
        for (int nt = 0; nt < 4; ++nt) {
            int k = w * 64 + nt * 16 + lr;
            #pragma unroll
            for (int e = 0; e < 4; ++e)
                ppv[nt][e] = PPB[mytok[e] * K_DIM + k];
        }
        // ---- macros 4..7 from LDS (zero vmem)
        COMPML(4) COMPML(5) COMPML(6) COMPML(7)
        LBAR;   // barrier1: Xb8 reads done, Lg visible

        // ---- P3: gating in fp32, rewrite Xb8 (fp8 only)
        #pragma unroll
        for (int nt = 0; nt < 4; ++nt) {
            int k = w * 64 + nt * 16 + lr;
            #pragma unroll
            for (int e = 0; e < 4; ++e) {
                float a  = (nt == 0) ? acc0[e] : (nt == 1) ? acc1[e]
                         : (nt == 2) ? acc2[e] : acc3[e];
                float nx = xm[nt][e] + ppv[nt][e][0] * (a - xm[nt][e]) + ppv[nt][e][1];
                xm[nt][e] = nx;
                Xb8[4 * lg + e][k] = f2fp8(nx);
            }
        }
        // waves 0..3: log-softmax + LL for 4 seqs each (16 lanes/seq, 4 logits/lane)
        if (w < 4) {
            int b = w * 4 + (l >> 4);
            int i = l & 15;
            float v[4];
            #pragma unroll
            for (int c = 0; c < 4; ++c)
                v[c] = Lg[0][b][i * 4 + c] + Lg[1][b][i * 4 + c];
            float m = fmaxf(fmaxf(v[0], v[1]), fmaxf(v[2], v[3]));
            m = fmaxf(m, __shfl_xor(m, 1));
            m = fmaxf(m, __shfl_xor(m, 2));
            m = fmaxf(m, __shfl_xor(m, 4));
            m = fmaxf(m, __shfl_xor(m, 8));
            float sum = expf(v[0] - m) + expf(v[1] - m) + expf(v[2] - m) + expf(v[3] - m);
            sum += __shfl_xor(sum, 1);
            sum += __shfl_xor(sum, 2);
            sum += __shfl_xor(sum, 4);
            sum += __shfl_xor(sum, 8);
            int tok = tokS[b][t];
            float sel = (i == (tok >> 2)) ? v[tok & 3] : 0.0f;
            sel += __shfl_xor(sel, 1);
            sel += __shfl_xor(sel, 2);
            sel += __shfl_xor(sel, 4);
            sel += __shfl_xor(sel, 8);
            llacc += sel - m - logf(sum);
        }
        LBAR;   // barrier2: new Xb8 visible, Lg consumed
    }

    if (w < 4 && (l & 15) == 0)
        out[b0 + w * 4 + (l >> 4)] = llacc;
}

extern "C" void kernel_launch(void* const* d_in, const int* in_sizes, int n_in,
                              void* d_out, int out_size, void* d_ws, size_t ws_size,
                              hipStream_t stream) {
    const float* A  = (const float*)d_in[0];   // (512,512)
    const float* B  = (const float*)d_in[1];   // (512,64)
    const float* C  = (const float*)d_in[2];   // (64,512)
    const float* Pp = (const float*)d_in[3];   // (64,512)
    const float* init = (const float*)d_in[4]; // (512,)
    const int* tokens = (const int*)d_in[5];   // (512,64)
    float* out = (float*)d_out;

    // workspace layout (needs 557,056 bytes)
    char*  A8  = (char*)d_ws;                                  // 512*512*1 = 262144
    char*  C8  = (char*)d_ws + 262144;                         // 64*512*1  =  32768
    f32x2* PPB = (f32x2*)((char*)d_ws + 294912);               // 64*512*8  = 262144

    ssm_prep<<<256, 256, 0, stream>>>(A, B, C, Pp, A8, C8, PPB);
    ssm_main<<<NWG, 512, 0, stream>>>(A8, C8, PPB, init, tokens, out);
}